// Round 7
// baseline (546.589 us; speedup 1.0000x reference)
//
#include <hip/hip_runtime.h>
#include <hip/hip_cooperative_groups.h>

namespace cg = cooperative_groups;

#define SAMPLES 32
#define ELEMS_PER_SAMPLE (256 * 64 * 64)              // 1048576
#define VEC4_PER_SAMPLE (ELEMS_PER_SAMPLE / 4)        // 262144
#define THREADS 256
#define GRID 2048
#define BPS 64                                        // blocks per sample
#define ITERS (VEC4_PER_SAMPLE / (BPS * THREADS))     // 16

#define BETA 2.0f
#define EPS 1e-5f

typedef float f32x4 __attribute__((ext_vector_type(4)));

__device__ __forceinline__ float wave_reduce_sum(float v) {
#pragma unroll
    for (int off = 32; off > 0; off >>= 1)
        v += __shfl_down(v, off, 64);
    return v;
}

__device__ __forceinline__ float smooth_l1(float d) {
    return (d <= BETA) ? (0.25f * d * d) : (d - 1.0f);
}

// ws layout (floats):
//   [0 .. 2*GRID)         per-block (sum, sumsq) pairs
//   [2*GRID .. 3*GRID)    per-block loss partials
//   [3*GRID]              completion counter (unsigned)
#define W_LPART (2 * GRID)
#define W_CTR (3 * GRID)

// ================= single cooperative kernel, full occupancy =================
__global__ __launch_bounds__(THREADS, 8) void kd_onepass_kernel(
    const f32x4* __restrict__ t, const f32x4* __restrict__ st,
    float* __restrict__ ws, float* __restrict__ out) {
    __shared__ float sm[2 * (THREADS / 64)];
    const int tid = threadIdx.x;
    const int lane = tid & 63;
    const int wid = tid >> 6;
    const size_t base = (size_t)blockIdx.x * (THREADS * ITERS);

    // ---- Phase A: teacher stats (identical loop to round-2 stats kernel) ----
    {
        float sum = 0.0f, sumsq = 0.0f;
#pragma unroll
        for (int i = 0; i < ITERS; ++i) {
            f32x4 v = t[base + i * THREADS + tid];
            sum += v.x + v.y + v.z + v.w;
            sumsq += v.x * v.x + v.y * v.y + v.z * v.z + v.w * v.w;
        }
        float s1 = wave_reduce_sum(sum);
        float s2 = wave_reduce_sum(sumsq);
        if (lane == 0) {
            sm[wid] = s1;
            sm[(THREADS / 64) + wid] = s2;
        }
        __syncthreads();
        if (tid == 0) {
            ws[2 * blockIdx.x]     = sm[0] + sm[1] + sm[2] + sm[3];
            ws[2 * blockIdx.x + 1] = sm[4] + sm[5] + sm[6] + sm[7];
            // reset the completion counter every call (poison/replay-safe):
            // all increments happen after grid.sync(), so this cannot race.
            if (blockIdx.x == 0) *(volatile unsigned*)&ws[W_CTR] = 0u;
        }
        __syncthreads();
    }

    __threadfence();
    cg::this_grid().sync();

    // ---- Phase B: per-sample stats from partials (L2-hot), then loss ----
    const int s = blockIdx.x / BPS;
    float psum = ws[2 * (s * BPS + lane)];
    float psumsq = ws[2 * (s * BPS + lane) + 1];
    psum = wave_reduce_sum(psum);
    psumsq = wave_reduce_sum(psumsq);
    psum = __shfl(psum, 0, 64);
    psumsq = __shfl(psumsq, 0, 64);

    const float inv_n = 1.0f / (float)ELEMS_PER_SAMPLE;
    const float mean = psum * inv_n;
    const float var = psumsq * inv_n - mean * mean;
    const float rstd = rsqrtf(var + EPS);
    const float nb = -mean * rstd;  // t_norm = fma(t, rstd, nb)

    float acc = 0.0f;
#pragma unroll
    for (int i = 0; i < ITERS; ++i) {
        const size_t idx = base + i * THREADS + tid;
        f32x4 tv = t[idx];
        f32x4 sv = st[idx];
        float d0 = fabsf(fmaf(tv.x, rstd, nb) - sv.x);
        float d1 = fabsf(fmaf(tv.y, rstd, nb) - sv.y);
        float d2 = fabsf(fmaf(tv.z, rstd, nb) - sv.z);
        float d3 = fabsf(fmaf(tv.w, rstd, nb) - sv.w);
        acc += smooth_l1(d0) + smooth_l1(d1) + smooth_l1(d2) + smooth_l1(d3);
    }

    {
        float a = wave_reduce_sum(acc);
        __syncthreads();
        if (lane == 0) sm[wid] = a;
        __syncthreads();
        if (tid == 0) ws[W_LPART + blockIdx.x] = sm[0] + sm[1] + sm[2] + sm[3];
    }

    // ---- last finishing block reduces all 2048 partials ----
    __shared__ bool last;
    if (tid == 0) {
        __threadfence();
        unsigned old = atomicAdd((unsigned*)&ws[W_CTR], 1u);
        last = (old == GRID - 1);
    }
    __syncthreads();
    if (last) {
        __threadfence();
        float a = 0.0f;
#pragma unroll
        for (int i = 0; i < GRID / THREADS; ++i)  // 8
            a += ws[W_LPART + i * THREADS + tid];
        a = wave_reduce_sum(a);
        __syncthreads();
        if (lane == 0) sm[wid] = a;
        __syncthreads();
        if (tid == 0)
            out[0] = (sm[0] + sm[1] + sm[2] + sm[3]) * (1.0f / (float)SAMPLES);
    }
}

// ================= fallback path (round-2 structure, proven 64.5 us) =========
__global__ __launch_bounds__(THREADS) void kd_stats_kernel(
    const f32x4* __restrict__ t, float* __restrict__ stats) {
    const size_t base = (size_t)blockIdx.x * (THREADS * ITERS);
    float sum = 0.0f, sumsq = 0.0f;
#pragma unroll
    for (int i = 0; i < ITERS; ++i) {
        f32x4 v = t[base + i * THREADS + threadIdx.x];
        sum += v.x + v.y + v.z + v.w;
        sumsq += v.x * v.x + v.y * v.y + v.z * v.z + v.w * v.w;
    }
    const int lane = threadIdx.x & 63;
    const int wid = threadIdx.x >> 6;
    sum = wave_reduce_sum(sum);
    sumsq = wave_reduce_sum(sumsq);
    __shared__ float sm[2 * (THREADS / 64)];
    if (lane == 0) {
        sm[wid] = sum;
        sm[(THREADS / 64) + wid] = sumsq;
    }
    __syncthreads();
    if (threadIdx.x == 0) {
        stats[2 * blockIdx.x]     = sm[0] + sm[1] + sm[2] + sm[3];
        stats[2 * blockIdx.x + 1] = sm[4] + sm[5] + sm[6] + sm[7];
    }
}

__global__ __launch_bounds__(THREADS) void kd_loss_kernel(
    const f32x4* __restrict__ t, const f32x4* __restrict__ st,
    const float* __restrict__ stats, float* __restrict__ lpart) {
    const int s = blockIdx.x / BPS;
    const int lane = threadIdx.x & 63;
    float psum = stats[2 * (s * BPS + lane)];
    float psumsq = stats[2 * (s * BPS + lane) + 1];
    psum = wave_reduce_sum(psum);
    psumsq = wave_reduce_sum(psumsq);
    psum = __shfl(psum, 0, 64);
    psumsq = __shfl(psumsq, 0, 64);

    const float inv_n = 1.0f / (float)ELEMS_PER_SAMPLE;
    const float mean = psum * inv_n;
    const float var = psumsq * inv_n - mean * mean;
    const float rstd = rsqrtf(var + EPS);

    const size_t base = (size_t)blockIdx.x * (THREADS * ITERS);
    float acc = 0.0f;
#pragma unroll
    for (int i = 0; i < ITERS; ++i) {
        const size_t idx = base + i * THREADS + threadIdx.x;
        f32x4 tv = t[idx];
        f32x4 sv = st[idx];
        float d0 = fabsf((tv.x - mean) * rstd - sv.x);
        float d1 = fabsf((tv.y - mean) * rstd - sv.y);
        float d2 = fabsf((tv.z - mean) * rstd - sv.z);
        float d3 = fabsf((tv.w - mean) * rstd - sv.w);
        acc += smooth_l1(d0) + smooth_l1(d1) + smooth_l1(d2) + smooth_l1(d3);
    }

    const int wid = threadIdx.x >> 6;
    acc = wave_reduce_sum(acc);
    __shared__ float sm[THREADS / 64];
    if (lane == 0) sm[wid] = acc;
    __syncthreads();
    if (threadIdx.x == 0)
        lpart[blockIdx.x] = sm[0] + sm[1] + sm[2] + sm[3];
}

__global__ __launch_bounds__(THREADS) void kd_final_kernel(
    const float* __restrict__ lpart, float* __restrict__ out) {
    float acc = 0.0f;
#pragma unroll
    for (int i = 0; i < GRID / THREADS; ++i)  // 8
        acc += lpart[i * THREADS + threadIdx.x];
    const int lane = threadIdx.x & 63;
    const int wid = threadIdx.x >> 6;
    acc = wave_reduce_sum(acc);
    __shared__ float sm[THREADS / 64];
    if (lane == 0) sm[wid] = acc;
    __syncthreads();
    if (threadIdx.x == 0)
        out[0] = (sm[0] + sm[1] + sm[2] + sm[3]) * (1.0f / (float)SAMPLES);
}

extern "C" void kernel_launch(void* const* d_in, const int* in_sizes, int n_in,
                              void* d_out, int out_size, void* d_ws,
                              size_t ws_size, hipStream_t stream) {
    const f32x4* teacher = (const f32x4*)d_in[0];
    const f32x4* student = (const f32x4*)d_in[1];
    float* out = (float*)d_out;
    float* ws = (float*)d_ws;

    void* args[4] = {(void*)&teacher, (void*)&student, (void*)&ws, (void*)&out};
    hipError_t e = hipLaunchCooperativeKernel(
        (void*)kd_onepass_kernel, dim3(GRID), dim3(THREADS), args, 0, stream);

    if (e != hipSuccess) {
        float* stats = ws;
        float* lpart = ws + W_LPART;
        kd_stats_kernel<<<GRID, THREADS, 0, stream>>>(teacher, stats);
        kd_loss_kernel<<<GRID, THREADS, 0, stream>>>(teacher, student, stats, lpart);
        kd_final_kernel<<<1, THREADS, 0, stream>>>(lpart, out);
    }
}

// Round 8
// 159.943 us; speedup vs baseline: 3.4174x; 3.4174x over previous
//
#include <hip/hip_runtime.h>

#define SAMPLES 32
#define ELEMS_PER_SAMPLE (256 * 64 * 64)              // 1048576
#define VEC4_PER_SAMPLE (ELEMS_PER_SAMPLE / 4)        // 262144
#define THREADS 256
#define GRID 2048
#define BPS 64                                        // blocks per sample
#define ITERS (VEC4_PER_SAMPLE / (BPS * THREADS))     // 16

#define BETA 2.0f
#define EPS 1e-5f

typedef float f32x4 __attribute__((ext_vector_type(4)));

__device__ __forceinline__ float wave_reduce_sum(float v) {
#pragma unroll
    for (int off = 32; off > 0; off >>= 1)
        v += __shfl_down(v, off, 64);
    return v;
}

__device__ __forceinline__ float smooth_l1(float d) {
    return (d <= BETA) ? (0.25f * d * d) : (d - 1.0f);
}

// ws layout (floats):
//   [0 .. 2*GRID)         per-block (sum, sumsq) pairs   (written by stats)
//   [2*GRID .. 3*GRID)    per-block loss partials        (written by loss)
//   [3*GRID]              completion counter (unsigned; zeroed by stats)
#define W_LPART (2 * GRID)
#define W_CTR (3 * GRID)

// ---------------- Kernel 1: per-block teacher partial sum/sumsq ----------------
__global__ __launch_bounds__(THREADS) void kd_stats_kernel(
    const f32x4* __restrict__ t, float* __restrict__ ws) {
    const size_t base = (size_t)blockIdx.x * (THREADS * ITERS);
    float sum = 0.0f, sumsq = 0.0f;
#pragma unroll
    for (int i = 0; i < ITERS; ++i) {
        f32x4 v = t[base + i * THREADS + threadIdx.x];
        sum += v.x + v.y + v.z + v.w;
        sumsq += v.x * v.x + v.y * v.y + v.z * v.z + v.w * v.w;
    }
    const int lane = threadIdx.x & 63;
    const int wid = threadIdx.x >> 6;
    sum = wave_reduce_sum(sum);
    sumsq = wave_reduce_sum(sumsq);
    __shared__ float sm[2 * (THREADS / 64)];
    if (lane == 0) {
        sm[wid] = sum;
        sm[(THREADS / 64) + wid] = sumsq;
    }
    __syncthreads();
    if (threadIdx.x == 0) {
        ws[2 * blockIdx.x]     = sm[0] + sm[1] + sm[2] + sm[3];
        ws[2 * blockIdx.x + 1] = sm[4] + sm[5] + sm[6] + sm[7];
        // Zero the loss kernel's completion counter. Stream ordering
        // guarantees this lands before any loss-kernel increment; done
        // every call so graph replays see a fresh counter (poison-safe).
        if (blockIdx.x == 0) *(volatile unsigned*)&ws[W_CTR] = 0u;
    }
}

// ---- Kernel 2: stats from partials + smooth-L1 + fused last-block reduce ----
__global__ __launch_bounds__(THREADS) void kd_loss_kernel(
    const f32x4* __restrict__ t, const f32x4* __restrict__ st,
    float* __restrict__ ws, float* __restrict__ out) {
    const int s = blockIdx.x / BPS;
    const int tid = threadIdx.x;
    const int lane = tid & 63;
    const int wid = tid >> 6;

    // Per-sample stats from the 64 L2-hot partial pairs (redundant per wave).
    float psum = ws[2 * (s * BPS + lane)];
    float psumsq = ws[2 * (s * BPS + lane) + 1];
    psum = wave_reduce_sum(psum);
    psumsq = wave_reduce_sum(psumsq);
    psum = __shfl(psum, 0, 64);
    psumsq = __shfl(psumsq, 0, 64);

    const float inv_n = 1.0f / (float)ELEMS_PER_SAMPLE;
    const float mean = psum * inv_n;
    const float var = psumsq * inv_n - mean * mean;
    const float rstd = rsqrtf(var + EPS);
    const float nb = -mean * rstd;  // t_norm = fma(t, rstd, nb)

    const size_t base = (size_t)blockIdx.x * (THREADS * ITERS);
    float acc = 0.0f;
#pragma unroll
    for (int i = 0; i < ITERS; ++i) {
        const size_t idx = base + i * THREADS + tid;
        f32x4 tv = __builtin_nontemporal_load(t + idx);
        f32x4 sv = __builtin_nontemporal_load(st + idx);
        float d0 = fabsf(fmaf(tv.x, rstd, nb) - sv.x);
        float d1 = fabsf(fmaf(tv.y, rstd, nb) - sv.y);
        float d2 = fabsf(fmaf(tv.z, rstd, nb) - sv.z);
        float d3 = fabsf(fmaf(tv.w, rstd, nb) - sv.w);
        acc += smooth_l1(d0) + smooth_l1(d1) + smooth_l1(d2) + smooth_l1(d3);
    }

    __shared__ float sm[THREADS / 64];
    acc = wave_reduce_sum(acc);
    if (lane == 0) sm[wid] = acc;
    __syncthreads();
    if (tid == 0)
        ws[W_LPART + blockIdx.x] = sm[0] + sm[1] + sm[2] + sm[3];

    // ---- fused final reduce: last finishing block sums all 2048 partials ----
    __shared__ bool last;
    if (tid == 0) {
        __threadfence();  // make our partial visible before counting in
        unsigned old = atomicAdd((unsigned*)&ws[W_CTR], 1u);
        last = (old == GRID - 1);
    }
    __syncthreads();
    if (last) {
        __threadfence();  // acquire: all partials visible
        float a = 0.0f;
#pragma unroll
        for (int i = 0; i < GRID / THREADS; ++i)  // 8
            a += ws[W_LPART + i * THREADS + tid];
        a = wave_reduce_sum(a);
        __syncthreads();
        if (lane == 0) sm[wid] = a;
        __syncthreads();
        if (tid == 0)
            out[0] = (sm[0] + sm[1] + sm[2] + sm[3]) * (1.0f / (float)SAMPLES);
    }
}

extern "C" void kernel_launch(void* const* d_in, const int* in_sizes, int n_in,
                              void* d_out, int out_size, void* d_ws,
                              size_t ws_size, hipStream_t stream) {
    const f32x4* teacher = (const f32x4*)d_in[0];
    const f32x4* student = (const f32x4*)d_in[1];
    float* out = (float*)d_out;
    float* ws = (float*)d_ws;

    kd_stats_kernel<<<GRID, THREADS, 0, stream>>>(teacher, ws);
    kd_loss_kernel<<<GRID, THREADS, 0, stream>>>(teacher, student, ws, out);
}

// Round 9
// 127.186 us; speedup vs baseline: 4.2975x; 1.2575x over previous
//
#include <hip/hip_runtime.h>

#define SAMPLES 32
#define ELEMS_PER_SAMPLE (256 * 64 * 64)              // 1048576
#define VEC4_PER_SAMPLE (ELEMS_PER_SAMPLE / 4)        // 262144
#define THREADS 256
#define GRID 2048
#define BPS 64                                        // blocks per sample
#define ITERS (VEC4_PER_SAMPLE / (BPS * THREADS))     // 16

#define BETA 2.0f
#define EPS 1e-5f

typedef float f32x4 __attribute__((ext_vector_type(4)));

__device__ __forceinline__ float wave_reduce_sum(float v) {
#pragma unroll
    for (int off = 32; off > 0; off >>= 1)
        v += __shfl_down(v, off, 64);
    return v;
}

__device__ __forceinline__ float smooth_l1(float d) {
    return (d <= BETA) ? (0.25f * d * d) : (d - 1.0f);
}

// ws layout (floats):
//   [0 .. 2*GRID)         per-block (sum, sumsq) pairs   (written by stats)
//   [2*GRID .. 3*GRID)    per-block loss partials        (written by loss)
//   [3*GRID]              completion counter (unsigned; zeroed by stats)
#define W_LPART (2 * GRID)
#define W_CTR (3 * GRID)

// ---------------- Kernel 1: per-block teacher partial sum/sumsq ----------------
// EXACT round-2 memory loop (93% of streaming peak). Plain loads only.
__global__ __launch_bounds__(THREADS) void kd_stats_kernel(
    const f32x4* __restrict__ t, float* __restrict__ ws) {
    const size_t base = (size_t)blockIdx.x * (THREADS * ITERS);
    float sum = 0.0f, sumsq = 0.0f;
#pragma unroll
    for (int i = 0; i < ITERS; ++i) {
        f32x4 v = t[base + i * THREADS + threadIdx.x];
        sum += v.x + v.y + v.z + v.w;
        sumsq += v.x * v.x + v.y * v.y + v.z * v.z + v.w * v.w;
    }
    const int lane = threadIdx.x & 63;
    const int wid = threadIdx.x >> 6;
    sum = wave_reduce_sum(sum);
    sumsq = wave_reduce_sum(sumsq);
    __shared__ float sm[2 * (THREADS / 64)];
    if (lane == 0) {
        sm[wid] = sum;
        sm[(THREADS / 64) + wid] = sumsq;
    }
    __syncthreads();
    if (threadIdx.x == 0) {
        ws[2 * blockIdx.x]     = sm[0] + sm[1] + sm[2] + sm[3];
        ws[2 * blockIdx.x + 1] = sm[4] + sm[5] + sm[6] + sm[7];
        // Zero the loss kernel's completion counter. Stream ordering puts
        // this before any loss-kernel increment; done every call so graph
        // replays see a fresh counter (poison-safe).
        if (blockIdx.x == 0) *(volatile unsigned*)&ws[W_CTR] = 0u;
    }
}

// ---- Kernel 2: stats from partials + smooth-L1 + fused last-block reduce ----
// EXACT round-2 memory loop (plain loads); only the tail is new.
__global__ __launch_bounds__(THREADS) void kd_loss_kernel(
    const f32x4* __restrict__ t, const f32x4* __restrict__ st,
    float* __restrict__ ws, float* __restrict__ out) {
    const int s = blockIdx.x / BPS;
    const int tid = threadIdx.x;
    const int lane = tid & 63;
    const int wid = tid >> 6;

    // Per-sample stats from the 64 L2-hot partial pairs (redundant per wave).
    float psum = ws[2 * (s * BPS + lane)];
    float psumsq = ws[2 * (s * BPS + lane) + 1];
    psum = wave_reduce_sum(psum);
    psumsq = wave_reduce_sum(psumsq);
    psum = __shfl(psum, 0, 64);
    psumsq = __shfl(psumsq, 0, 64);

    const float inv_n = 1.0f / (float)ELEMS_PER_SAMPLE;
    const float mean = psum * inv_n;
    const float var = psumsq * inv_n - mean * mean;
    const float rstd = rsqrtf(var + EPS);

    const size_t base = (size_t)blockIdx.x * (THREADS * ITERS);
    float acc = 0.0f;
#pragma unroll
    for (int i = 0; i < ITERS; ++i) {
        const size_t idx = base + i * THREADS + tid;
        f32x4 tv = t[idx];
        f32x4 sv = st[idx];
        float d0 = fabsf((tv.x - mean) * rstd - sv.x);
        float d1 = fabsf((tv.y - mean) * rstd - sv.y);
        float d2 = fabsf((tv.z - mean) * rstd - sv.z);
        float d3 = fabsf((tv.w - mean) * rstd - sv.w);
        acc += smooth_l1(d0) + smooth_l1(d1) + smooth_l1(d2) + smooth_l1(d3);
    }

    __shared__ float sm[THREADS / 64];
    acc = wave_reduce_sum(acc);
    if (lane == 0) sm[wid] = acc;
    __syncthreads();
    if (tid == 0)
        ws[W_LPART + blockIdx.x] = sm[0] + sm[1] + sm[2] + sm[3];

    // ---- fused final reduce: last finishing block sums all 2048 partials ----
    __shared__ bool last;
    if (tid == 0) {
        __threadfence();  // make our partial visible before counting in
        unsigned old = atomicAdd((unsigned*)&ws[W_CTR], 1u);
        last = (old == GRID - 1);
    }
    __syncthreads();
    if (last) {
        __threadfence();  // acquire: all partials visible
        float a = 0.0f;
#pragma unroll
        for (int i = 0; i < GRID / THREADS; ++i)  // 8
            a += ws[W_LPART + i * THREADS + tid];
        a = wave_reduce_sum(a);
        __syncthreads();
        if (lane == 0) sm[wid] = a;
        __syncthreads();
        if (tid == 0)
            out[0] = (sm[0] + sm[1] + sm[2] + sm[3]) * (1.0f / (float)SAMPLES);
    }
}

extern "C" void kernel_launch(void* const* d_in, const int* in_sizes, int n_in,
                              void* d_out, int out_size, void* d_ws,
                              size_t ws_size, hipStream_t stream) {
    const f32x4* teacher = (const f32x4*)d_in[0];
    const f32x4* student = (const f32x4*)d_in[1];
    float* out = (float*)d_out;
    float* ws = (float*)d_ws;

    kd_stats_kernel<<<GRID, THREADS, 0, stream>>>(teacher, ws);
    kd_loss_kernel<<<GRID, THREADS, 0, stream>>>(teacher, student, ws, out);
}

// Round 10
// 124.686 us; speedup vs baseline: 4.3837x; 1.0201x over previous
//
#include <hip/hip_runtime.h>

#define SAMPLES 32
#define ELEMS_PER_SAMPLE (256 * 64 * 64)              // 1048576
#define VEC4_PER_SAMPLE (ELEMS_PER_SAMPLE / 4)        // 262144
#define THREADS 256
#define GRID 2048
#define BPS 64                                        // blocks per sample
#define ITERS (VEC4_PER_SAMPLE / (BPS * THREADS))     // 16

#define BETA 2.0f
#define EPS 1e-5f

typedef float f32x4 __attribute__((ext_vector_type(4)));

__device__ __forceinline__ float wave_reduce_sum(float v) {
#pragma unroll
    for (int off = 32; off > 0; off >>= 1)
        v += __shfl_down(v, off, 64);
    return v;
}

__device__ __forceinline__ float smooth_l1(float d) {
    return (d <= BETA) ? (0.25f * d * d) : (d - 1.0f);
}

// ws layout (floats):
//   [0 .. 2*GRID)         per-block (sum, sumsq) pairs   (written by stats)
//   [2*GRID .. 3*GRID)    per-block loss partials        (agent-scope atomics)
//   [3*GRID]              completion counter (unsigned; zeroed by stats)
#define W_LPART (2 * GRID)
#define W_CTR (3 * GRID)

// ---------------- Kernel 1: per-block teacher partial sum/sumsq ----------------
// EXACT round-2 memory loop (93% of streaming peak). Plain loads only.
__global__ __launch_bounds__(THREADS) void kd_stats_kernel(
    const f32x4* __restrict__ t, float* __restrict__ ws) {
    const size_t base = (size_t)blockIdx.x * (THREADS * ITERS);
    float sum = 0.0f, sumsq = 0.0f;
#pragma unroll
    for (int i = 0; i < ITERS; ++i) {
        f32x4 v = t[base + i * THREADS + threadIdx.x];
        sum += v.x + v.y + v.z + v.w;
        sumsq += v.x * v.x + v.y * v.y + v.z * v.z + v.w * v.w;
    }
    const int lane = threadIdx.x & 63;
    const int wid = threadIdx.x >> 6;
    sum = wave_reduce_sum(sum);
    sumsq = wave_reduce_sum(sumsq);
    __shared__ float sm[2 * (THREADS / 64)];
    if (lane == 0) {
        sm[wid] = sum;
        sm[(THREADS / 64) + wid] = sumsq;
    }
    __syncthreads();
    if (threadIdx.x == 0) {
        ws[2 * blockIdx.x]     = sm[0] + sm[1] + sm[2] + sm[3];
        ws[2 * blockIdx.x + 1] = sm[4] + sm[5] + sm[6] + sm[7];
        // Zero the loss kernel's completion counter (agent-scope, no fence).
        // Kernel-boundary ordering puts this before any loss increment;
        // done every call so graph replays see a fresh counter.
        if (blockIdx.x == 0)
            __hip_atomic_store((unsigned*)&ws[W_CTR], 0u, __ATOMIC_RELAXED,
                               __HIP_MEMORY_SCOPE_AGENT);
    }
}

// ---- Kernel 2: stats from partials + smooth-L1 + fused last-block reduce ----
// Main loop byte-for-byte round 2. Tail uses agent-scoped atomics ONLY —
// no __threadfence() (which emits whole-L2 writeback+invalidate on CDNA
// and thrashed rounds 8/9).
__global__ __launch_bounds__(THREADS) void kd_loss_kernel(
    const f32x4* __restrict__ t, const f32x4* __restrict__ st,
    float* __restrict__ ws, float* __restrict__ out) {
    const int s = blockIdx.x / BPS;
    const int tid = threadIdx.x;
    const int lane = tid & 63;
    const int wid = tid >> 6;

    // Per-sample stats from the 64 L2-hot partial pairs (redundant per wave).
    float psum = ws[2 * (s * BPS + lane)];
    float psumsq = ws[2 * (s * BPS + lane) + 1];
    psum = wave_reduce_sum(psum);
    psumsq = wave_reduce_sum(psumsq);
    psum = __shfl(psum, 0, 64);
    psumsq = __shfl(psumsq, 0, 64);

    const float inv_n = 1.0f / (float)ELEMS_PER_SAMPLE;
    const float mean = psum * inv_n;
    const float var = psumsq * inv_n - mean * mean;
    const float rstd = rsqrtf(var + EPS);

    const size_t base = (size_t)blockIdx.x * (THREADS * ITERS);
    float acc = 0.0f;
#pragma unroll
    for (int i = 0; i < ITERS; ++i) {
        const size_t idx = base + i * THREADS + tid;
        f32x4 tv = t[idx];
        f32x4 sv = st[idx];
        float d0 = fabsf((tv.x - mean) * rstd - sv.x);
        float d1 = fabsf((tv.y - mean) * rstd - sv.y);
        float d2 = fabsf((tv.z - mean) * rstd - sv.z);
        float d3 = fabsf((tv.w - mean) * rstd - sv.w);
        acc += smooth_l1(d0) + smooth_l1(d1) + smooth_l1(d2) + smooth_l1(d3);
    }

    __shared__ float sm[THREADS / 64];
    acc = wave_reduce_sum(acc);
    if (lane == 0) sm[wid] = acc;
    __syncthreads();

    // Publish partial via agent-scope store (coherent per-access, no fence).
    if (tid == 0)
        __hip_atomic_store(&ws[W_LPART + blockIdx.x],
                           sm[0] + sm[1] + sm[2] + sm[3], __ATOMIC_RELAXED,
                           __HIP_MEMORY_SCOPE_AGENT);

    // Last finishing block reduces all 2048 partials.
    __shared__ bool last;
    if (tid == 0) {
        unsigned old = __hip_atomic_fetch_add((unsigned*)&ws[W_CTR], 1u,
                                              __ATOMIC_ACQ_REL,
                                              __HIP_MEMORY_SCOPE_AGENT);
        last = (old == GRID - 1);
    }
    __syncthreads();
    if (last) {
        float a = 0.0f;
#pragma unroll
        for (int i = 0; i < GRID / THREADS; ++i)  // 8
            a += __hip_atomic_load(&ws[W_LPART + i * THREADS + tid],
                                   __ATOMIC_RELAXED, __HIP_MEMORY_SCOPE_AGENT);
        a = wave_reduce_sum(a);
        __syncthreads();
        if (lane == 0) sm[wid] = a;
        __syncthreads();
        if (tid == 0)
            out[0] = (sm[0] + sm[1] + sm[2] + sm[3]) * (1.0f / (float)SAMPLES);
    }
}

extern "C" void kernel_launch(void* const* d_in, const int* in_sizes, int n_in,
                              void* d_out, int out_size, void* d_ws,
                              size_t ws_size, hipStream_t stream) {
    const f32x4* teacher = (const f32x4*)d_in[0];
    const f32x4* student = (const f32x4*)d_in[1];
    float* out = (float*)d_out;
    float* ws = (float*)d_ws;

    kd_stats_kernel<<<GRID, THREADS, 0, stream>>>(teacher, ws);
    kd_loss_kernel<<<GRID, THREADS, 0, stream>>>(teacher, student, ws, out);
}